// Round 8
// baseline (1258.729 us; speedup 1.0000x reference)
//
#include <hip/hip_runtime.h>
#include <math.h>

#define TFRAMES 4096
#define DM 128
#define LQ 64
#define NG 16
#define NH 8
#define DQH 16
#define FD 2048
#define GFD 512
#define PAD 63
#define KVROWS (TFRAMES + PAD)      /* 4159 */
#define ASTRIDE (KVROWS * DM)       /* 532352 SHORTS per bf16 K/V array */
#define FPB 4                       /* frames per block */
#define MROWS (FPB * NG)            /* 64 state rows per block */
#define STS 136                     /* state row stride (shorts, mult of 8) */
#define VTS 72                      /* V^T row stride (shorts) */
#define PBS 72                      /* P buffer row stride (shorts) */
#define UROWS (LQ + FPB - 1)        /* 67 K/V union rows */

/* ws layout (floats) */
#define OFF_WVH  0
#define OFF_WVL  131072
#define OFF_WKVH 262144
#define OFF_WKVL 294912
#define OFF_KV   (TFRAMES * DM)
#define OFF_TEXT (OFF_KV + 2 * ASTRIDE)
#define OFF_KF   (OFF_TEXT + NG * DM)
#define OFF_VF   (OFF_KF + NG * DM)
#define OFF_W1T  (OFF_VF + NG * DM)
#define OFF_W2T  (OFF_W1T + 262144)
#define OFF_WQT  (OFF_W2T + 262144)
#define OFF_WQFT (OFF_WQT + 16384)

typedef __attribute__((ext_vector_type(8))) short bf16x8;
typedef __attribute__((ext_vector_type(4))) float f32x4;
#define MFMA16(a, b, c) __builtin_amdgcn_mfma_f32_16x16x32_bf16(a, b, c, 0, 0, 0)

__device__ __forceinline__ short bfc(float x) {
    union { float f; unsigned u; } v; v.f = x;
    unsigned r = v.u + 0x7fffu + ((v.u >> 16) & 1u);   // RNE
    return (short)(r >> 16);
}
__device__ __forceinline__ float b2f(short s) {
    union { unsigned u; float f; } v;
    v.u = ((unsigned)(unsigned short)s) << 16;
    return v.f;
}
#ifndef __has_builtin
#define __has_builtin(x) 0
#endif
#if __has_builtin(__builtin_amdgcn_cvt_pk_bf16_f32)
typedef __attribute__((ext_vector_type(2))) __bf16 bf2_t;
__device__ __forceinline__ unsigned pkbf(float a, float b) {
    bf2_t r = __builtin_amdgcn_cvt_pk_bf16_f32(a, b);    // v_cvt_pk_bf16_f32 (RNE)
    union { bf2_t v; unsigned u; } c; c.v = r; return c.u;
}
#else
__device__ __forceinline__ unsigned pkbf(float a, float b) {
    return (unsigned)(unsigned short)bfc(a) | ((unsigned)(unsigned short)bfc(b) << 16);
}
#endif
// Extract 8 shorts at short-offset f (0..3) from 12-short window {a, b.x, b.y}.
// alignbit shift is 5-bit (wraps at 32) -> word-select + 0/16-bit residual.
__device__ __forceinline__ bf16x8 shiftf(int4 a, int4 b, int f) {
    const int wo = f >> 1;
    const int sh = (f & 1) * 16;
    int w0 = wo ? a.y : a.x;
    int w1 = wo ? a.z : a.y;
    int w2 = wo ? a.w : a.z;
    int w3 = wo ? b.x : a.w;
    int w4 = wo ? b.y : b.x;
    int o0 = __builtin_amdgcn_alignbit(w1, w0, sh);
    int o1 = __builtin_amdgcn_alignbit(w2, w1, sh);
    int o2 = __builtin_amdgcn_alignbit(w3, w2, sh);
    int o3 = __builtin_amdgcn_alignbit(w4, w3, sh);
    int4 o = {o0, o1, o2, o3};
    return *(bf16x8*)&o;
}

// -------- kernel W1: bf16 transposed weights (+ hi/lo Wk/Wv) -----------------
__global__ __launch_bounds__(256) void k_wcvt(const float* __restrict__ Wq_enc,
                                              const float* __restrict__ W1f,
                                              const float* __restrict__ W2f,
                                              const float* __restrict__ Wqf,
                                              const float* __restrict__ Wk_enc,
                                              const float* __restrict__ Wv_enc,
                                              short* __restrict__ W1T,
                                              short* __restrict__ W2T,
                                              short* __restrict__ WQT,
                                              short* __restrict__ WQFT,
                                              short* __restrict__ WKVH,
                                              short* __restrict__ WKVL) {
    const int t = blockIdx.x * 256 + threadIdx.x;
    const int gsel = blockIdx.y;
    if (gsel < 2) {
        int n = t >> 7, k = t & 127;
        W1T[gsel * 262144 + t] = bfc(W1f[(size_t)gsel * 262144 + (size_t)k * FD + n]);
    } else if (gsel < 4) {
        int l = gsel - 2;
        int n = t >> 11, k = t & 2047;
        W2T[l * 262144 + t] = bfc(W2f[(size_t)l * 262144 + (size_t)k * DM + n]);
    } else if (gsel < 6) {
        int l = gsel - 4;
        if (t < 16384) {
            int n = t >> 7, k = t & 127;
            WQT[l * 16384 + t] = bfc(Wq_enc[(size_t)l * 16384 + k * DM + n]);
        }
    } else if (gsel == 6) {
        if (t < 16384) {
            int n = t >> 7, k = t & 127;
            WQFT[t] = bfc(Wqf[(size_t)k * DM + n]);
        }
    } else {
        if (t < 65536) {
            int a = t >> 14, rem = t & 16383;
            int n = rem >> 7, k = rem & 127;
            const float* src = ((a & 1) ? Wv_enc : Wk_enc) + (size_t)(a >> 1) * 16384;
            float v = src[k * 128 + n];
            short hi = bfc(v);
            WKVH[t] = hi;
            WKVL[t] = bfc(v - b2f(hi));
        }
    }
}

// -------- kernel W2: Wvis^T hi/lo via coalesced LDS tile transpose -----------
__global__ __launch_bounds__(256) void k_wvt(const float* __restrict__ Wvis,
                                             short* __restrict__ WVH,
                                             short* __restrict__ WVL) {
    __shared__ float tile[64][65];
    const int tid = threadIdx.x;
    const int k0 = blockIdx.x * 64;
    const int n0 = blockIdx.y * 64;
    for (int o = tid; o < 64 * 64; o += 256) {
        int r = o >> 6, c = o & 63;
        tile[r][c] = Wvis[(size_t)(k0 + r) * DM + n0 + c];
    }
    __syncthreads();
    for (int o = tid; o < 64 * 64; o += 256) {
        int rn = o >> 6, ck = o & 63;
        float v = tile[ck][rn];
        short hi = bfc(v);
        WVH[(size_t)(n0 + rn) * FD + k0 + ck] = hi;
        WVL[(size_t)(n0 + rn) * FD + k0 + ck] = bfc(v - b2f(hi));
    }
}

// -------- kernel P: visual=lf@Wvis, LN, K/V=visn@Wk/Wv — MFMA, hi/lo ---------
__global__ __launch_bounds__(256) void k_viskv(const float* __restrict__ lf,
                                               const short* __restrict__ WVH,
                                               const short* __restrict__ WVL,
                                               const short* __restrict__ WKVH,
                                               const short* __restrict__ WKVL,
                                               short* __restrict__ kvB) {
    __shared__ __align__(16) char smem[17408 + 4352];
    __shared__ float sPa[256], sPb[256], sMean[16], sRstd[16];
    short* Ah = (short*)smem;                 // [16][136]
    short* Al = (short*)(smem + 4352);
    float* vis = (float*)smem;                // [16][132] fp32 (overlays Ah/Al)
    short* Vh = (short*)(smem + 8704);
    short* Vl = (short*)(smem + 13056);

    const int tid = threadIdx.x;              // 256 = 4 waves
    const int w = tid >> 6;
    const int lane = tid & 63;
    const int lq = lane & 15;
    const int quad = lane >> 4;
    const int r0 = blockIdx.x * 16;

    // ---- phase 1: visual = lf @ Wvis, software-pipelined staging ----
    f32x4 acc[2];
    acc[0] = (f32x4){0.f, 0.f, 0.f, 0.f};
    acc[1] = (f32x4){0.f, 0.f, 0.f, 0.f};
    float pre[8];
#pragma unroll
    for (int i = 0; i < 8; ++i) {
        int o = tid + 256 * i;
        pre[i] = lf[(size_t)(r0 + (o >> 7)) * FD + (o & 127)];
    }
    for (int c = 0; c < 16; ++c) {
        __syncthreads();                      // prior MFMA reads done
#pragma unroll
        for (int i = 0; i < 8; ++i) {
            int o = tid + 256 * i;
            int r = o >> 7, j = o & 127;
            float v = pre[i];
            short hi = bfc(v);
            Ah[r * 136 + j] = hi;
            Al[r * 136 + j] = bfc(v - b2f(hi));
        }
        __syncthreads();
        if (c < 15) {
#pragma unroll
            for (int i = 0; i < 8; ++i) {     // prefetch next chunk (overlaps MFMA)
                int o = tid + 256 * i;
                pre[i] = lf[(size_t)(r0 + (o >> 7)) * FD + (c + 1) * 128 + (o & 127)];
            }
        }
#pragma unroll
        for (int ks = 0; ks < 4; ++ks) {
            bf16x8 ah = *(const bf16x8*)&Ah[lq * 136 + ks * 32 + quad * 8];
            bf16x8 al = *(const bf16x8*)&Al[lq * 136 + ks * 32 + quad * 8];
#pragma unroll
            for (int nt = 0; nt < 2; ++nt) {
                const size_t bo = (size_t)(w * 32 + nt * 16 + lq) * FD + c * 128 + ks * 32 + quad * 8;
                bf16x8 bh = *(const bf16x8*)&WVH[bo];
                bf16x8 bl = *(const bf16x8*)&WVL[bo];
                acc[nt] = MFMA16(ah, bh, acc[nt]);
                acc[nt] = MFMA16(al, bh, acc[nt]);
                acc[nt] = MFMA16(ah, bl, acc[nt]);
            }
        }
    }
    __syncthreads();
#pragma unroll
    for (int nt = 0; nt < 2; ++nt)
#pragma unroll
        for (int r = 0; r < 4; ++r)
            vis[(quad * 4 + r) * 132 + w * 32 + nt * 16 + lq] = acc[nt][r];
    __syncthreads();

    // ---- phase 2: LN; visn -> hi/lo bf16 ----
    {
        int row = tid >> 4, p = tid & 15;
        float s = 0.f, s2 = 0.f;
#pragma unroll
        for (int k = 0; k < 8; ++k) { float v = vis[row * 132 + p * 8 + k]; s += v; s2 += v * v; }
        sPa[tid] = s; sPb[tid] = s2;
    }
    __syncthreads();
    if (tid < 16) {
        float s = 0.f, s2 = 0.f;
#pragma unroll
        for (int p = 0; p < 16; ++p) { s += sPa[tid * 16 + p]; s2 += sPb[tid * 16 + p]; }
        float m = s * (1.f / 128.f);
        float v = s2 * (1.f / 128.f) - m * m;
        sMean[tid] = m; sRstd[tid] = rsqrtf(v + 1e-5f);
    }
    __syncthreads();
    for (int o = tid; o < 16 * 128; o += 256) {
        int r = o >> 7, j = o & 127;
        float v = (vis[r * 132 + j] - sMean[r]) * sRstd[r];
        short hi = bfc(v);
        Vh[r * 136 + j] = hi;
        Vl[r * 136 + j] = bfc(v - b2f(hi));
    }
    __syncthreads();

    // ---- phase 3: K/V = visn @ Wk/Wv, bf16 out ----
    for (int a = 0; a < 4; ++a) {
        f32x4 ka[2];
        ka[0] = (f32x4){0.f, 0.f, 0.f, 0.f};
        ka[1] = (f32x4){0.f, 0.f, 0.f, 0.f};
#pragma unroll
        for (int ks = 0; ks < 4; ++ks) {
            bf16x8 ah = *(const bf16x8*)&Vh[lq * 136 + ks * 32 + quad * 8];
            bf16x8 al = *(const bf16x8*)&Vl[lq * 136 + ks * 32 + quad * 8];
#pragma unroll
            for (int nt = 0; nt < 2; ++nt) {
                const size_t bo = (size_t)a * 16384 + (size_t)(w * 32 + nt * 16 + lq) * 128 + ks * 32 + quad * 8;
                bf16x8 bh = *(const bf16x8*)&WKVH[bo];
                bf16x8 bl = *(const bf16x8*)&WKVL[bo];
                ka[nt] = MFMA16(ah, bh, ka[nt]);
                ka[nt] = MFMA16(al, bh, ka[nt]);
                ka[nt] = MFMA16(ah, bl, ka[nt]);
            }
        }
#pragma unroll
        for (int nt = 0; nt < 2; ++nt)
#pragma unroll
            for (int r = 0; r < 4; ++r)
                kvB[(size_t)a * ASTRIDE + (size_t)(PAD + r0 + quad * 4 + r) * DM + w * 32 + nt * 16 + lq]
                    = bfc(ka[nt][r]);
    }
}

// -------- kernel 3: text = g @ W_txt ; Kf / Vf -------------------------------
__global__ __launch_bounds__(128) void k_text(const float* __restrict__ g,
                                              const float* __restrict__ Wtxt,
                                              const float* __restrict__ Wkf,
                                              const float* __restrict__ Wvf,
                                              float* __restrict__ text,
                                              float* __restrict__ kf,
                                              float* __restrict__ vf) {
    __shared__ float gs[GFD];
    __shared__ float tr[DM];
    const int r = blockIdx.x;
    const int tid = threadIdx.x;
    for (int i = tid; i < GFD; i += 128) gs[i] = g[(size_t)r * GFD + i];
    __syncthreads();
    float acc = 0.f;
    for (int k = 0; k < GFD; ++k) acc += gs[k] * Wtxt[(size_t)k * DM + tid];
    tr[tid] = acc;
    text[(size_t)r * DM + tid] = acc;
    __syncthreads();
    float a1 = 0.f, a2 = 0.f;
    for (int k = 0; k < DM; ++k) {
        float x = tr[k];
        a1 += x * Wkf[(size_t)k * DM + tid];
        a2 += x * Wvf[(size_t)k * DM + tid];
    }
    kf[(size_t)r * DM + tid] = a1;
    vf[(size_t)r * DM + tid] = a2;
}

// ---------------- LN helpers for [64][STS] bf16 LDS tile ---------------------
__device__ __forceinline__ void ln_stats64(const short* buf, int tid, int dbl,
                                           float* pa, float* pb, float* ms, float* rs) {
    {
        int row = tid >> 3, p = tid & 7;
        const bf16x8* bp = (const bf16x8*)(buf + row * STS + p * 16);
        float s = 0.f, s2 = 0.f;
#pragma unroll
        for (int q8 = 0; q8 < 2; ++q8) {
            bf16x8 x = bp[q8];
#pragma unroll
            for (int e = 0; e < 8; ++e) { float v = b2f(x[e]); s += v; s2 += v * v; }
        }
        pa[tid] = s; pb[tid] = s2;
    }
    __syncthreads();
    if (tid < 64) {
        float ss = 0.f, ss2 = 0.f;
#pragma unroll
        for (int p2 = 0; p2 < 8; ++p2) { ss += pa[tid * 8 + p2]; ss2 += pb[tid * 8 + p2]; }
        float m = ss * (1.f / 128.f);
        float v = ss2 * (1.f / 128.f) - m * m;
        float r = rsqrtf(v + 1e-5f);
        if (dbl) r *= rsqrtf(v / (v + 1e-5f) + 1e-5f);   // exact LN(LN(x)) fold
        ms[tid] = m; rs[tid] = r;
    }
    __syncthreads();
}
__device__ __forceinline__ void ln_apply64(short* buf, int tid,
                                           const float* ms, const float* rs) {
    int row = tid >> 3, p = tid & 7;
    float m = ms[row], r = rs[row];
    bf16x8* bp = (bf16x8*)(buf + row * STS + p * 16);
#pragma unroll
    for (int q8 = 0; q8 < 2; ++q8) {
        bf16x8 x = bp[q8];
        unsigned u0 = pkbf((b2f(x[0]) - m) * r, (b2f(x[1]) - m) * r);
        unsigned u1 = pkbf((b2f(x[2]) - m) * r, (b2f(x[3]) - m) * r);
        unsigned u2 = pkbf((b2f(x[4]) - m) * r, (b2f(x[5]) - m) * r);
        unsigned u3 = pkbf((b2f(x[6]) - m) * r, (b2f(x[7]) - m) * r);
        int4 o = {(int)u0, (int)u1, (int)u2, (int)u3};
        bp[q8] = *(bf16x8*)&o;
    }
    __syncthreads();
}

// ---------------- kernel 4: 4 frames/block, MFMA attention + FFN -------------
__global__ __launch_bounds__(512, 4) void k_frames(
    const short* __restrict__ kvB,    const float* __restrict__ text,
    const float* __restrict__ kf,     const float* __restrict__ vf,
    const short* __restrict__ W1T,    const short* __restrict__ W2T,
    const short* __restrict__ WQT,    const short* __restrict__ WQFT,
    float* __restrict__ out) {
    // one pool: sT | sX | R (sVT+sPB during attn; wave-private H / Yred during FFN) | sPa | sPb | stats
    __shared__ __align__(16) char pool[76288];
    short* sT  = (short*)pool;                    // 64*136 sh = 17408 B
    short* sX  = (short*)(pool + 17408);          // 17408 B
    char*  R   = pool + 34816;                    // 36864 B
    short* sVT = (short*)R;                       // 128*72 sh = 18432 B (attention)
    short* sPB = (short*)(R + 18432);             // 18432 B (attention P / final kf,vf,sc)
    float* sPa = (float*)(pool + 71680);
    float* sPb = (float*)(pool + 73728);
    float* sMean = (float*)(pool + 75776);
    float* sRstd = (float*)(pool + 76032);

    const int tid = threadIdx.x;        // 512 = 8 waves
    const int w = tid >> 6;
    const int lane = tid & 63;
    const int lq = lane & 15;
    const int quad = lane >> 4;
    const int T0 = blockIdx.x * FPB;

    for (int o = tid; o < MROWS * 128; o += 512)
        sT[(o >> 7) * STS + (o & 127)] = bfc(text[((o >> 7) & 15) * 128 + (o & 127)]);
    __syncthreads();

    for (int l = 0; l < 2; ++l) {
        const short* kvK = kvB + (size_t)(2 * l) * ASTRIDE;
        const short* kvV = kvB + (size_t)(2 * l + 1) * ASTRIDE;

        // ---- stage V^T union + LN stats of t ----
        for (int o = tid; o < UROWS * 128; o += 512) {
            int u = o >> 7, d = o & 127;
            sVT[d * VTS + u] = kvV[(size_t)(T0 + u) * 128 + d];
        }
        ln_stats64(sT, tid, 0, sPa, sPb, sMean, sRstd);

        // ---- Q = LN(t) @ Wq[l] -> sX (LN inline on A-fragments, pk converts) ----
        {
            const short* wq = WQT + (size_t)l * 16384;
            bf16x8 B[4];
#pragma unroll
            for (int ks = 0; ks < 4; ++ks)
                B[ks] = *(const bf16x8*)&wq[(w * 16 + lq) * 128 + ks * 32 + quad * 8];
#pragma unroll
            for (int mt = 0; mt < 4; ++mt) {
                int row = mt * 16 + lq;
                float m = sMean[row], r = sRstd[row];
                f32x4 acc = {0.f, 0.f, 0.f, 0.f};
#pragma unroll
                for (int ks = 0; ks < 4; ++ks) {
                    bf16x8 t8 = *(const bf16x8*)&sT[row * STS + ks * 32 + quad * 8];
                    unsigned u0 = pkbf((b2f(t8[0]) - m) * r, (b2f(t8[1]) - m) * r);
                    unsigned u1 = pkbf((b2f(t8[2]) - m) * r, (b2f(t8[3]) - m) * r);
                    unsigned u2 = pkbf((b2f(t8[4]) - m) * r, (b2f(t8[5]) - m) * r);
                    unsigned u3 = pkbf((b2f(t8[6]) - m) * r, (b2f(t8[7]) - m) * r);
                    int4 ai = {(int)u0, (int)u1, (int)u2, (int)u3};
                    acc = MFMA16(*(bf16x8*)&ai, B[ks], acc);
                }
#pragma unroll
                for (int r4 = 0; r4 < 4; ++r4)
                    sX[(mt * 16 + quad * 4 + r4) * STS + w * 16 + lq] = bfc(acc[r4]);
            }
        }
        __syncthreads();

        // ---- attention: wave pair (2f, 2f+1) -> frame f, 4 heads each ----
        {
            const int f = w >> 1;
            const int hg = (w & 1) * 4;
            short* Pb = sPB + w * 16 * PBS;
            bf16x8 zv = {};
            for (int hh = 0; hh < 4; ++hh) {
                const int h = hg + hh;
                bf16x8 aq;
                {
                    bf16x8 t8 = *(const bf16x8*)&sX[(f * 16 + lq) * STS + h * 16 + (quad & 1) * 8];
                    aq = (quad < 2) ? t8 : zv;
                }
                f32x4 sc4[4];
#pragma unroll
                for (int kt = 0; kt < 4; ++kt) {
                    bf16x8 bk = *(const bf16x8*)&kvK[(size_t)(T0 + f + kt * 16 + lq) * 128 + h * 16 + (quad & 1) * 8];
                    bk = (quad < 2) ? bk : zv;
                    f32x4 z4 = {0.f, 0.f, 0.f, 0.f};
                    sc4[kt] = MFMA16(aq, bk, z4);
                }
                float pr[4][4];
#pragma unroll
                for (int r = 0; r < 4; ++r) {
                    float a0 = sc4[0][r] * 0.25f, a1 = sc4[1][r] * 0.25f;
                    float a2 = sc4[2][r] * 0.25f, a3 = sc4[3][r] * 0.25f;
                    float mx = fmaxf(fmaxf(a0, a1), fmaxf(a2, a3));
                    mx = fmaxf(mx, __shfl_xor(mx, 1));
                    mx = fmaxf(mx, __shfl_xor(mx, 2));
                    mx = fmaxf(mx, __shfl_xor(mx, 4));
                    mx = fmaxf(mx, __shfl_xor(mx, 8));
                    float e0 = expf(a0 - mx), e1 = expf(a1 - mx);
                    float e2 = expf(a2 - mx), e3 = expf(a3 - mx);
                    float s = e0 + e1 + e2 + e3;
                    s += __shfl_xor(s, 1);
                    s += __shfl_xor(s, 2);
                    s += __shfl_xor(s, 4);
                    s += __shfl_xor(s, 8);
                    float inv = 1.f / s;
                    pr[r][0] = e0 * inv; pr[r][1] = e1 * inv;
                    pr[r][2] = e2 * inv; pr[r][3] = e3 * inv;
                }
                const short* vr = &sVT[(h * 16 + lq) * VTS];
                int4 v0 = *(const int4*)&vr[quad * 8];
                int4 v1 = *(const int4*)&vr[quad * 8 + 8];
                int4 u0 = *(const int4*)&vr[32 + quad * 8];
                int4 u1 = *(const int4*)&vr[32 + quad * 8 + 8];
                bf16x8 b0 = shiftf(v0, v1, f);
                bf16x8 b1 = shiftf(u0, u1, f);
                // PV hi pass
                float hif[4][4];
#pragma unroll
                for (int r = 0; r < 4; ++r) {
                    unsigned ha = pkbf(pr[r][0], pr[r][1]);
                    unsigned hb = pkbf(pr[r][2], pr[r][3]);
                    hif[r][0] = b2f((short)ha); hif[r][1] = b2f((short)(ha >> 16));
                    hif[r][2] = b2f((short)hb); hif[r][3] = b2f((short)(hb >> 16));
                    Pb[(quad * 4 + r) * PBS + 0  + lq] = (short)ha;
                    Pb[(quad * 4 + r) * PBS + 16 + lq] = (short)(ha >> 16);
                    Pb[(quad * 4 + r) * PBS + 32 + lq] = (short)hb;
                    Pb[(quad * 4 + r) * PBS + 48 + lq] = (short)(hb >> 16);
                }
                f32x4 ctx = {0.f, 0.f, 0.f, 0.f};
                {
                    bf16x8 p0 = *(const bf16x8*)&Pb[lq * PBS + quad * 8];
                    bf16x8 p1 = *(const bf16x8*)&Pb[lq * PBS + 32 + quad * 8];
                    ctx = MFMA16(p0, b0, ctx);
                    ctx = MFMA16(p1, b1, ctx);
                }
                // PV lo pass (wave-private ordering via lgkmcnt)
#pragma unroll
                for (int r = 0; r < 4; ++r) {
                    unsigned la = pkbf(pr[r][0] - hif[r][0], pr[r][1] - hif[r][1]);
                    unsigned lb = pkbf(pr[r][2] - hif[r][2], pr[r][3] - hif[r][3]);
                    Pb[(quad * 4 + r) * PBS + 0  + lq] = (short)la;
                    Pb[(quad * 4 + r) * PBS + 16 + lq] = (short)(la >> 16);
                    Pb[(quad * 4 + r) * PBS + 32 + lq] = (short)lb;
                    Pb[(quad * 4 + r) * PBS + 48 + lq] = (short)(lb >> 16);
                }
                {
                    bf16x8 p0 = *(const bf16x8*)&Pb[lq * PBS + quad * 8];
                    bf16x8 p1 = *(const bf16x8*)&Pb[lq * PBS + 32 + quad * 8];
                    ctx = MFMA16(p0, b0, ctx);
                    ctx = MFMA16(p1, b1, ctx);
                }
                // z = ctx + tq
                {
                    int row0 = f * 16 + quad * 4;
                    int col = h * 16 + lq;
                    float z0 = ctx[0] + (b2f(sT[(row0 + 0) * STS + col]) - sMean[row0 + 0]) * sRstd[row0 + 0];
                    float z1 = ctx[1] + (b2f(sT[(row0 + 1) * STS + col]) - sMean[row0 + 1]) * sRstd[row0 + 1];
                    float z2 = ctx[2] + (b2f(sT[(row0 + 2) * STS + col]) - sMean[row0 + 2]) * sRstd[row0 + 2];
                    float z3 = ctx[3] + (b2f(sT[(row0 + 3) * STS + col]) - sMean[row0 + 3]) * sRstd[row0 + 3];
                    unsigned za = pkbf(z0, z1), zb = pkbf(z2, z3);
                    sT[(row0 + 0) * STS + col] = (short)za;
                    sT[(row0 + 1) * STS + col] = (short)(za >> 16);
                    sT[(row0 + 2) * STS + col] = (short)zb;
                    sT[(row0 + 3) * STS + col] = (short)(zb >> 16);
                }
            }
        }
        __syncthreads();

        // ---- x = LN(LN(z)) in place ----
        ln_stats64(sT, tid, 1, sPa, sPb, sMean, sRstd);
        ln_apply64(sT, tid, sMean, sRstd);

        // ---- FFN: wave-private H chunks (no inner barriers), K-split x2 ----
        // wave w = kw*4 + mw: m-tile mw (16 rows), K-half kw (chunks kw*8..kw*8+7)
        {
            const short* w1p = W1T + (size_t)l * 262144;
            const short* w2p = W2T + (size_t)l * 262144;
            const int mw = w & 3, kw = w >> 2;
            short* Hw = (short*)(R + w * 4352);            // [16][136] bf16, wave-private
            float* Yred = (float*)R;                       // [4][16][132] fp32 (after barrier)
            bf16x8 XA[4];
#pragma unroll
            for (int ks = 0; ks < 4; ++ks)
                XA[ks] = *(const bf16x8*)&sT[(mw * 16 + lq) * STS + ks * 32 + quad * 8];
            f32x4 yacc[8];
#pragma unroll
            for (int nt = 0; nt < 8; ++nt) yacc[nt] = (f32x4){0.f, 0.f, 0.f, 0.f};
            for (int cc = 0; cc < 8; ++cc) {
                const int c = kw * 8 + cc;
                // GEMM1: H chunk [16 m][128 n] -> Hw (relu, pk converts)
#pragma unroll
                for (int nt = 0; nt < 8; ++nt) {
                    f32x4 h = {0.f, 0.f, 0.f, 0.f};
#pragma unroll
                    for (int ks = 0; ks < 4; ++ks) {
                        bf16x8 B1 = *(const bf16x8*)&w1p[(size_t)(c * 128 + nt * 16 + lq) * 128 + ks * 32 + quad * 8];
                        h = MFMA16(XA[ks], B1, h);
                    }
                    unsigned p01 = pkbf(fmaxf(h[0], 0.f), fmaxf(h[1], 0.f));
                    unsigned p23 = pkbf(fmaxf(h[2], 0.f), fmaxf(h[3], 0.f));
                    int cH = nt * 16 + lq;
                    Hw[(quad * 4 + 0) * 136 + cH] = (short)p01;
                    Hw[(quad * 4 + 1) * 136 + cH] = (short)(p01 >> 16);
                    Hw[(quad * 4 + 2) * 136 + cH] = (short)p23;
                    Hw[(quad * 4 + 3) * 136 + cH] = (short)(p23 >> 16);
                }
                // GEMM2: consume chunk immediately (same-wave LDS ordering)
#pragma unroll
                for (int ks2 = 0; ks2 < 4; ++ks2) {
                    bf16x8 A = *(const bf16x8*)&Hw[lq * 136 + ks2 * 32 + quad * 8];
#pragma unroll
                    for (int nt = 0; nt < 8; ++nt) {
                        bf16x8 B2 = *(const bf16x8*)&w2p[(size_t)(nt * 16 + lq) * 2048 + c * 128 + ks2 * 32 + quad * 8];
                        yacc[nt] = MFMA16(A, B2, yacc[nt]);
                    }
                }
            }
            __syncthreads();   // all H dead; all yacc final
            if (kw == 1) {
#pragma unroll
                for (int nt = 0; nt < 8; ++nt)
#pragma unroll
                    for (int r = 0; r < 4; ++r)
                        Yred[(mw * 16 + quad * 4 + r) * 132 + nt * 16 + lq] = yacc[nt][r];
            }
            __syncthreads();
            if (kw == 0) {
#pragma unroll
                for (int nt = 0; nt < 8; ++nt) {
                    int col = nt * 16 + lq;
                    int row0 = mw * 16 + quad * 4;
                    float z0 = yacc[nt][0] + Yred[(row0 + 0) * 132 + col] + b2f(sT[(row0 + 0) * STS + col]);
                    float z1 = yacc[nt][1] + Yred[(row0 + 1) * 132 + col] + b2f(sT[(row0 + 1) * STS + col]);
                    float z2 = yacc[nt][2] + Yred[(row0 + 2) * 132 + col] + b2f(sT[(row0 + 2) * STS + col]);
                    float z3 = yacc[nt][3] + Yred[(row0 + 3) * 132 + col] + b2f(sT[(row0 + 3) * STS + col]);
                    unsigned za = pkbf(z0, z1), zb = pkbf(z2, z3);
                    sT[(row0 + 0) * STS + col] = (short)za;
                    sT[(row0 + 1) * STS + col] = (short)(za >> 16);
                    sT[(row0 + 2) * STS + col] = (short)zb;
                    sT[(row0 + 3) * STS + col] = (short)(zb >> 16);
                }
            }
            __syncthreads();
        }

        // ---- t = LN(z2) in place ----
        ln_stats64(sT, tid, 0, sPa, sPb, sMean, sRstd);
        ln_apply64(sT, tid, sMean, sRstd);
    }

    // ================= final single-head attention (d_q = 128) ==============
    {
        bf16x8 B[4];
#pragma unroll
        for (int ks = 0; ks < 4; ++ks)
            B[ks] = *(const bf16x8*)&WQFT[(w * 16 + lq) * 128 + ks * 32 + quad * 8];
#pragma unroll
        for (int mt = 0; mt < 4; ++mt) {
            f32x4 acc = {0.f, 0.f, 0.f, 0.f};
#pragma unroll
            for (int ks = 0; ks < 4; ++ks) {
                bf16x8 A = *(const bf16x8*)&sT[(mt * 16 + lq) * STS + ks * 32 + quad * 8];
                acc = MFMA16(A, B[ks], acc);
            }
#pragma unroll
            for (int r = 0; r < 4; ++r)
                sX[(mt * 16 + quad * 4 + r) * STS + w * 16 + lq] = bfc(acc[r]);
        }
    }
    short* kfL = sPB;
    short* vfL = sPB + 16 * STS;
    float* scF = (float*)(sPB + 2 * 16 * STS);       // [64][17] fp32
    for (int o = tid; o < 2048; o += 512) {
        kfL[(o >> 7) * STS + (o & 127)] = bfc(kf[o]);
        vfL[(o >> 7) * STS + (o & 127)] = bfc(vf[o]);
    }
    __syncthreads();
    if (tid < 256) {
        int m = tid >> 2, kq = tid & 3;
        float a4[4] = {0.f, 0.f, 0.f, 0.f};
        for (int d8 = 0; d8 < 16; ++d8) {
            bf16x8 qc = *(const bf16x8*)&sX[m * STS + d8 * 8];
            float qf[8];
#pragma unroll
            for (int e = 0; e < 8; ++e) qf[e] = b2f(qc[e]);
#pragma unroll
            for (int k = 0; k < 4; ++k) {
                bf16x8 kc = *(const bf16x8*)&kfL[(kq * 4 + k) * STS + d8 * 8];
#pragma unroll
                for (int e = 0; e < 8; ++e) a4[k] += qf[e] * b2f(kc[e]);
            }
        }
#pragma unroll
        for (int k = 0; k < 4; ++k)
            scF[m * 17 + kq * 4 + k] = a4[k] * 0.08838834764831845f;
    }
    __syncthreads();
    if (tid < 64) {
        float* row = scF + tid * 17;
        float mx = row[0];
#pragma unroll
        for (int k = 1; k < 16; ++k) mx = fmaxf(mx, row[k]);
        float sum = 0.f;
#pragma unroll
        for (int k = 0; k < 16; ++k) { float e = expf(row[k] - mx); row[k] = e; sum += e; }
        float inv = 1.f / sum;
#pragma unroll
        for (int k = 0; k < 16; ++k) row[k] *= inv;
    }
    __syncthreads();
    {
        int jj = tid & 127, rr0 = tid >> 7;
        float vv[16];
#pragma unroll
        for (int k = 0; k < 16; ++k) vv[k] = b2f(vfL[k * STS + jj]);
#pragma unroll 4
        for (int rr = 0; rr < 16; ++rr) {
            int row = rr0 + 4 * rr;
            float acc = 0.f;
#pragma unroll
            for (int k = 0; k < 16; ++k) acc += scF[row * 17 + k] * vv[k];
            sX[row * STS + jj] = bfc(acc + b2f(sT[row * STS + jj]));
        }
    }
    __syncthreads();
    ln_stats64(sX, tid, 0, sPa, sPb, sMean, sRstd);
    for (int o = tid; o < MROWS * 128; o += 512) {
        int r = o >> 7;
        out[(size_t)T0 * 2048 + o] = (b2f(sX[r * STS + (o & 127)]) - sMean[r]) * sRstd[r];
    }
}

extern "C" void kernel_launch(void* const* d_in, const int* in_sizes, int n_in,
                              void* d_out, int out_size, void* d_ws, size_t ws_size,
                              hipStream_t stream) {
    const float* g      = (const float*)d_in[0];
    const float* lf     = (const float*)d_in[1];
    const float* Wvis   = (const float*)d_in[2];
    const float* Wtxt   = (const float*)d_in[3];
    const float* Wq_enc = (const float*)d_in[4];
    const float* Wk_enc = (const float*)d_in[5];
    const float* Wv_enc = (const float*)d_in[6];
    const float* W1f    = (const float*)d_in[7];
    const float* W2f    = (const float*)d_in[8];
    const float* Wqf    = (const float*)d_in[9];
    const float* Wkf    = (const float*)d_in[10];
    const float* Wvf    = (const float*)d_in[11];
    float* out = (float*)d_out;
    float* ws  = (float*)d_ws;

    short* WVH  = (short*)(ws + OFF_WVH);
    short* WVL  = (short*)(ws + OFF_WVL);
    short* WKVH = (short*)(ws + OFF_WKVH);
    short* WKVL = (short*)(ws + OFF_WKVL);
    short* kvB  = (short*)(ws + OFF_KV);
    float* text = ws + OFF_TEXT;
    float* kfp  = ws + OFF_KF;
    float* vfp  = ws + OFF_VF;
    short* W1T  = (short*)(ws + OFF_W1T);
    short* W2T  = (short*)(ws + OFF_W2T);
    short* WQT  = (short*)(ws + OFF_WQT);
    short* WQFT = (short*)(ws + OFF_WQFT);

    for (int a = 0; a < 4; ++a)
        hipMemsetAsync(kvB + (size_t)a * ASTRIDE, 0, (size_t)PAD * DM * sizeof(short), stream);

    k_wcvt <<<dim3(1024, 8), dim3(256), 0, stream>>>(Wq_enc, W1f, W2f, Wqf, Wk_enc, Wv_enc,
                                                     W1T, W2T, WQT, WQFT, WKVH, WKVL);
    k_wvt  <<<dim3(32, 2), dim3(256), 0, stream>>>(Wvis, WVH, WVL);
    k_viskv<<<dim3(TFRAMES / 16), dim3(256), 0, stream>>>(lf, WVH, WVL, WKVH, WKVL, kvB);
    k_text <<<dim3(NG), dim3(128), 0, stream>>>(g, Wtxt, Wkf, Wvf, text, kfp, vfp);
    k_frames<<<dim3(TFRAMES / FPB), dim3(512), 0, stream>>>(kvB, text, kfp, vfp, W1T, W2T, WQT, WQFT, out);
}